// Round 12
// baseline (20234.879 us; speedup 1.0000x reference)
//
#include <hip/hip_runtime.h>
#include <hip/hip_bf16.h>

typedef __bf16 bf16;
typedef __bf16 bf16x8 __attribute__((ext_vector_type(8)));
typedef float  f32x4  __attribute__((ext_vector_type(4)));
typedef unsigned long long u64;

#define MFMA16(a,b,c) __builtin_amdgcn_mfma_f32_16x16x32_bf16((a),(b),(c),0,0,0)
#define NSTEP 119
#define NBLK 256

// ws offsets. bf16-elem offsets for weights; frag = 1024 bf16 [hi512|lo512].
#define O_L0   0u          // pair-split: ((m*8+nt)*10 + kt)*3 + gate
#define O_L1   491520u     // ((m*8+nt)*16 + kt)*3 + gate
#define O_L2   1277952u
#define O_Z2H  2064384u    // simple: (c*4+kt)
#define O_OUTW 2260992u    // simple: (tt*8+kg)
#define EXG_U  573440u     // u64 index (byte 4587520): 128*3*2*2048 u64
#define TOKI   4292608u    // int index: 128*2*16
#define FLGI   4296704u    // int index: 256 flags, stride 16 ints

#define FOFF(m,k) (((k)>>5)*512 + ((m) + 16*(((k)>>3)&3))*8 + ((k)&7))

__device__ __forceinline__ f32x4 splat4(float v){ f32x4 r={v,v,v,v}; return r; }
__device__ __forceinline__ float sigf(float x){ return 1.f/(1.f+expf(-x)); }
__device__ __forceinline__ unsigned pk2(float a, float b){
  union { __bf16 h[2]; unsigned u; } x; x.h[0]=(bf16)a; x.h[1]=(bf16)b; return x.u; }
__device__ __forceinline__ float upk(unsigned u, int i){
  union { __bf16 h[2]; unsigned u; } x; x.u=u; return (float)x.h[i]; }

__global__ void flg_init(int* wsi) {
  int i = blockIdx.x * 256 + threadIdx.x;
  if (i < 4096) wsi[FLGI + i] = 0;
}

// simple pack (z2h, outw): frag idx c*KTg + ktoff + ktm
__global__ void pack2s(const float* __restrict__ src, bf16* __restrict__ dst,
                       int Rt, int KTm, int KTg, int ktoff, int K) {
  int idx = blockIdx.x * 256 + threadIdx.x;
  if (idx >= Rt * KTm * 64) return;
  int lane = idx & 63, fi = idx >> 6;
  int r15 = lane & 15, q = lane >> 4;
  int c = fi / KTm, ktm = fi - c * KTm;
  const float* s = src + (size_t)(c * 16 + r15) * K + ktm * 32 + q * 8;
  bf16* d = dst + (size_t)(c * KTg + ktoff + ktm) * 1024 + lane * 8;
  #pragma unroll
  for (int e = 0; e < 8; ++e) {
    float v = s[e]; bf16 hi = (bf16)v;
    d[e] = hi; d[e + 512] = (bf16)(v - (float)hi);
  }
}

// pair-split pack (gate matrices [768][K]): member m owns col-tiles 2nt+m.
// dst frag idx = ((m*8+nt)*KTg + ktoff+ktm)*3 + gate
__global__ void pack2p(const float* __restrict__ src, bf16* __restrict__ dst,
                       int KTm, int KTg, int ktoff, int K) {
  int idx = blockIdx.x * 256 + threadIdx.x;
  if (idx >= 2 * 8 * KTm * 3 * 64) return;
  int lane = idx & 63, fi = idx >> 6;
  int r15 = lane & 15, q = lane >> 4;
  int gate = fi % 3; int t1 = fi / 3;
  int ktm = t1 % KTm; int t2 = t1 / KTm;
  int nt = t2 & 7, mm = t2 >> 3;
  const float* s = src + (size_t)(gate * 256 + (2 * nt + mm) * 16 + r15) * K + ktm * 32 + q * 8;
  bf16* d = dst + ((size_t)((mm * 8 + nt) * KTg + ktoff + ktm) * 3 + gate) * 1024 + lane * 8;
  #pragma unroll
  for (int e = 0; e < 8; ++e) {
    float v = s[e]; bf16 hi = (bf16)v;
    d[e] = hi; d[e + 512] = (bf16)(v - (float)hi);
  }
}

__device__ __forceinline__ void gl16(bf16x8& d, const bf16* p) {
  asm volatile("global_load_dwordx4 %0, %1, off" : "=v"(d) : "v"(p));
}

// One wave: 16 rows (rt half) x one neuron-tile's 3 gates, fused K = [in|h].
// B stream asm-pinned ring-2, counted vmcnt(6) (T4), sched_barrier (rule #18).
template<int KTI, int KT>
__device__ __forceinline__ void gemmP(
    f32x4& aR, f32x4& aZ, f32x4& aI, f32x4& aH,
    const bf16* __restrict__ Ai0, const bf16* __restrict__ Ai1,
    const bf16* __restrict__ Ah0, const bf16* __restrict__ Ah1,
    const bf16* __restrict__ BS, const int lane)
{
  const bf16* bp = BS + lane * 8;
  bf16x8 rb[2][3][2];
  asm volatile("s_waitcnt vmcnt(0)" ::: "memory");
  __builtin_amdgcn_sched_barrier(0);
  #pragma unroll
  for (int g3 = 0; g3 < 3; ++g3) {
    gl16(rb[0][g3][0], bp + g3 * 1024);
    gl16(rb[0][g3][1], bp + g3 * 1024 + 512);
  }
  #pragma unroll
  for (int kt = 0; kt < KT; ++kt) {
    const int s = kt & 1;
    if (kt + 1 < KT) {
      #pragma unroll
      for (int g3 = 0; g3 < 3; ++g3) {
        gl16(rb[s ^ 1][g3][0], bp + (size_t)((kt + 1) * 3 + g3) * 1024);
        gl16(rb[s ^ 1][g3][1], bp + (size_t)((kt + 1) * 3 + g3) * 1024 + 512);
      }
      asm volatile("s_waitcnt vmcnt(6)" ::: "memory");
    } else {
      asm volatile("s_waitcnt vmcnt(0)" ::: "memory");
    }
    __builtin_amdgcn_sched_barrier(0);
    const bf16* A0 = (kt < KTI) ? Ai0 : Ah0;
    const bf16* A1 = (kt < KTI) ? Ai1 : Ah1;
    const int ka   = (kt < KTI) ? kt : kt - KTI;
    bf16x8 a0 = *(const bf16x8*)(A0 + ka * 512 + lane * 8);
    bf16x8 a1 = *(const bf16x8*)(A1 + ka * 512 + lane * 8);
    aR = MFMA16(a0, rb[s][0][0], aR); aR = MFMA16(a1, rb[s][0][0], aR); aR = MFMA16(a0, rb[s][0][1], aR);
    aZ = MFMA16(a0, rb[s][1][0], aZ); aZ = MFMA16(a1, rb[s][1][0], aZ); aZ = MFMA16(a0, rb[s][1][1], aZ);
    f32x4& aN = (kt < KTI) ? aI : aH;
    aN = MFMA16(a0, rb[s][2][0], aN); aN = MFMA16(a1, rb[s][2][0], aN); aN = MFMA16(a0, rb[s][2][1], aN);
  }
}

__device__ __forceinline__ void updP(bf16* __restrict__ hc0, bf16* __restrict__ hc1,
    const f32x4 aR, const f32x4 aZ, const f32x4 aI, const f32x4 aH,
    unsigned (&cc)[2], const int q, const int j)
{
  float c2v[4] = { upk(cc[0],0), upk(cc[0],1), upk(cc[1],0), upk(cc[1],1) };
  #pragma unroll
  for (int r = 0; r < 4; ++r) {
    const int off = FOFF(q * 4 + r, j);
    float rg = sigf(aR[r]);
    float zg = sigf(aZ[r]);
    float ng = tanhf(aI[r] + rg * aH[r]);
    float hp = (float)hc0[off] + (float)hc1[off] + c2v[r];
    float hv = (1.f - zg) * ng + zg * hp;
    bf16 d0 = (bf16)hv; float r1 = hv - (float)d0;
    bf16 d1 = (bf16)r1; c2v[r] = r1 - (float)d1;
    hc0[off] = d0; hc1[off] = d1;
  }
  cc[0] = pk2(c2v[0], c2v[1]); cc[1] = pk2(c2v[2], c2v[3]);
}

__global__ __launch_bounds__(1024, 4)
void moldec_mfma(const float* __restrict__ z, const float* __restrict__ emb,
                 const float* __restrict__ z2h_b, const float* __restrict__ out_b,
                 const float* __restrict__ bih0, const float* __restrict__ bhh0,
                 const float* __restrict__ bih1, const float* __restrict__ bhh1,
                 const float* __restrict__ bih2, const float* __restrict__ bhh2,
                 const bf16* __restrict__ wsb, int* __restrict__ wsi,
                 u64* __restrict__ wsu, float* __restrict__ out)
{
  __shared__ __align__(16) bf16 hS[3][2][2][4096];  // [layer][comp][rt][8kt*512]
  __shared__ __align__(16) bf16 xzS[2][2][2048];    // [comp][rt][4kt*512]
  __shared__ float logS2[4][16][68];
  __shared__ float bS[4608];
  __shared__ float obS[64];
  __shared__ int tokS[32];

  const int tid = threadIdx.x, wave = tid >> 6, lane = tid & 63;
  const int q = lane >> 4, r15 = lane & 15;
  const int g = blockIdx.x & 127, mm = blockIdx.x >> 7;
  const int b0 = g * 32;
  const int nt = wave >> 1, rt = wave & 1;
  const int j = (2 * nt + mm) * 16 + r15;      // owned gate col in step loop
  int* flg_own = wsi + FLGI + (g * 2 + mm) * 16;
  int* flg_oth = wsi + FLGI + (g * 2 + (mm ^ 1)) * 16;

  // ---- biases -> LDS ----
  {
    const float* bp_[6] = {bih0, bhh0, bih1, bhh1, bih2, bhh2};
    for (int i = tid; i < 4608; i += 1024) {
      int l = i / 1536, w2 = (i % 1536) / 768, gg = i % 768;
      bS[i] = bp_[l * 2 + w2][gg];
    }
    if (tid < 64) obS[tid] = out_b[tid];
  }

  // ---- stage z (32 rows x 128) ----
  {
    const int m = tid >> 5, c4 = (tid & 31) * 4;
    const int rz = m >> 4, mz = m & 15;
    float4 v = *(const float4*)(z + (size_t)(b0 + m) * 128 + c4);
    const float vv[4] = {v.x, v.y, v.z, v.w};
    #pragma unroll
    for (int e = 0; e < 4; ++e) {
      int off = FOFF(mz, c4 + e);
      bf16 hi = (bf16)vv[e];
      xzS[0][rz][off] = hi;
      xzS[1][rz][off] = (bf16)(vv[e] - (float)hi);
    }
  }
  __syncthreads();

  unsigned c2p[3][2];   // h comp2 residual (owned cols), packed bf16 pairs
  #pragma unroll
  for (int l = 0; l < 3; ++l) { c2p[l][0] = 0u; c2p[l][1] = 0u; }

  // ---- h0 = tanh(z @ z2h_w.T + b): full (non-split) init, both members ----
  {
    const int wv = wave;       // 16 col-tiles of 16
    const int jz = wv * 16 + r15;
    f32x4 acc[2][3];
    #pragma unroll
    for (int rr = 0; rr < 2; ++rr)
      #pragma unroll
      for (int t = 0; t < 3; ++t) acc[rr][t] = splat4(z2h_b[t * 256 + jz]);
    #pragma unroll
    for (int kt = 0; kt < 4; ++kt) {
      #pragma unroll
      for (int rr = 0; rr < 2; ++rr) {
        bf16x8 a0 = *(const bf16x8*)(&xzS[0][rr][kt * 512 + lane * 8]);
        bf16x8 a1 = *(const bf16x8*)(&xzS[1][rr][kt * 512 + lane * 8]);
        #pragma unroll
        for (int t = 0; t < 3; ++t) {
          const bf16* bb = wsb + O_Z2H + (size_t)((wv + t * 16) * 4 + kt) * 1024 + lane * 8;
          bf16x8 b0 = *(const bf16x8*)bb;
          bf16x8 b1 = *(const bf16x8*)(bb + 512);
          acc[rr][t] = MFMA16(a0, b0, acc[rr][t]);
          acc[rr][t] = MFMA16(a1, b0, acc[rr][t]);
          acc[rr][t] = MFMA16(a0, b1, acc[rr][t]);
        }
      }
    }
    #pragma unroll
    for (int t = 0; t < 3; ++t)
      #pragma unroll
      for (int rr = 0; rr < 2; ++rr)
        #pragma unroll
        for (int r = 0; r < 4; ++r) {
          int off = rr * 4096 + FOFF(q * 4 + r, jz);
          float hv = tanhf(acc[rr][t][r]);
          bf16 d0 = (bf16)hv; float r1 = hv - (float)d0;
          (&hS[t][0][0][0])[off] = d0;
          (&hS[t][1][0][0])[off] = (bf16)r1;   // residual beyond d1 -> dropped (2^-17, once)
        }
  }
  // ---- stage x = emb[1] (rows 2w, 2w+1) ----
  {
    float ev = emb[64 + lane];
    bf16 hi = (bf16)ev, lo = (bf16)(ev - (float)hi);
    #pragma unroll
    for (int k2 = 0; k2 < 2; ++k2) {
      int rr = wave * 2 + k2;
      int rz = rr >> 4, mz = rr & 15, off = FOFF(mz, lane);
      xzS[0][rz][off] = hi; xzS[1][rz][off] = lo;
    }
  }
  __syncthreads();

  for (int step = 0; step < NSTEP; ++step) {
    const int base = step * 4;

    #pragma unroll 1
    for (int l = 0; l < 3; ++l) {
      // ---- setbias + fused GEMM for member's half of gate-cols ----
      const float* bl = bS + l * 1536;
      f32x4 aR = splat4(bl[j] + bl[768 + j]);
      f32x4 aZ = splat4(bl[256 + j] + bl[768 + 256 + j]);
      f32x4 aI = splat4(bl[512 + j]);
      f32x4 aH = splat4(bl[768 + 512 + j]);
      if (l == 0) {
        gemmP<2, 10>(aR, aZ, aI, aH,
                     &xzS[0][rt][0], &xzS[1][rt][0],
                     &hS[0][0][rt][0], &hS[0][1][rt][0],
                     wsb + O_L0 + (size_t)(mm * 8 + nt) * 30 * 1024, lane);
      } else if (l == 1) {
        gemmP<8, 16>(aR, aZ, aI, aH,
                     &hS[0][0][rt][0], &hS[0][1][rt][0],
                     &hS[1][0][rt][0], &hS[1][1][rt][0],
                     wsb + O_L1 + (size_t)(mm * 8 + nt) * 48 * 1024, lane);
      } else {
        gemmP<8, 16>(aR, aZ, aI, aH,
                     &hS[1][0][rt][0], &hS[1][1][rt][0],
                     &hS[2][0][rt][0], &hS[2][1][rt][0],
                     wsb + O_L2 + (size_t)(mm * 8 + nt) * 48 * 1024, lane);
      }
      __syncthreads();
      updP(&hS[l][0][rt][0], &hS[l][1][rt][0], aR, aZ, aI, aH, c2p[l], q, j);

      // ---- h-half exchange via relaxed AGENT atomics (no fences -> no L2 inv) ----
      __syncthreads();
      bf16* hbase = &hS[l][0][0][0];
      const size_t bown = ((size_t)(g * 3 + l) * 2 + mm) * 2048;
      const size_t both = ((size_t)(g * 3 + l) * 2 + (mm ^ 1)) * 2048;
      #pragma unroll
      for (int i = 0; i < 2; ++i) {
        int u = tid * 2 + i, e0 = u * 4;
        int off = e0 & 255, comp = (e0 >> 8) & 1, rr = (e0 >> 9) & 1, kt2 = e0 >> 10;
        union { bf16 h[4]; u64 v; } x;
        const bf16* s = hbase + comp * 8192 + rr * 4096 + kt2 * 512 + mm * 256 + off;
        x.h[0] = s[0]; x.h[1] = s[1]; x.h[2] = s[2]; x.h[3] = s[3];
        __hip_atomic_store(wsu + EXG_U + bown + u, x.v, __ATOMIC_RELAXED, __HIP_MEMORY_SCOPE_AGENT);
      }
      __syncthreads();   // drains vmcnt: stores at coherence point before flag
      if (tid == 0) {
        __hip_atomic_store(flg_own, base + l + 1, __ATOMIC_RELAXED, __HIP_MEMORY_SCOPE_AGENT);
        for (int it = 0; it < 20000000; ++it) {
          if (__hip_atomic_load(flg_oth, __ATOMIC_RELAXED, __HIP_MEMORY_SCOPE_AGENT) >= base + l + 1) break;
          __builtin_amdgcn_s_sleep(2);
        }
      }
      __syncthreads();
      #pragma unroll
      for (int i = 0; i < 2; ++i) {
        int u = tid * 2 + i, e0 = u * 4;
        int off = e0 & 255, comp = (e0 >> 8) & 1, rr = (e0 >> 9) & 1, kt2 = e0 >> 10;
        union { bf16 h[4]; u64 v; } x;
        x.v = __hip_atomic_load(wsu + EXG_U + both + u, __ATOMIC_RELAXED, __HIP_MEMORY_SCOPE_AGENT);
        bf16* d = hbase + comp * 8192 + rr * 4096 + kt2 * 512 + (mm ^ 1) * 256 + off;
        d[0] = x.h[0]; d[1] = x.h[1]; d[2] = x.h[2]; d[3] = x.h[3];
      }
      __syncthreads();
    }

    // ---- logits for member's 16 rows: wave = (ks, tt) ----
    {
      const int ks = wave >> 2, tt = wave & 3;
      f32x4 acc = (ks == 0) ? splat4(obS[tt * 16 + r15]) : splat4(0.f);
      #pragma unroll
      for (int k2 = 0; k2 < 2; ++k2) {
        int kg = ks * 2 + k2;
        bf16x8 a0 = *(const bf16x8*)(&hS[2][0][mm][kg * 512 + lane * 8]);
        bf16x8 a1 = *(const bf16x8*)(&hS[2][1][mm][kg * 512 + lane * 8]);
        const bf16* bb = wsb + O_OUTW + (size_t)(tt * 8 + kg) * 1024 + lane * 8;
        bf16x8 b0 = *(const bf16x8*)bb;
        bf16x8 b1 = *(const bf16x8*)(bb + 512);
        acc = MFMA16(a0, b0, acc);
        acc = MFMA16(a1, b0, acc);
        acc = MFMA16(a0, b1, acc);
      }
      #pragma unroll
      for (int r = 0; r < 4; ++r)
        logS2[ks][q * 4 + r][tt * 16 + r15] = acc[r];
    }
    __syncthreads();

    // ---- store + argmax (wave = local row), token exchange, stage x' ----
    {
      float v = logS2[0][wave][lane] + logS2[1][wave][lane]
              + logS2[2][wave][lane] + logS2[3][wave][lane];
      out[((size_t)(b0 + mm * 16 + wave) * NSTEP + step) * 64 + lane] = v;
      float bv = v; int bi = lane;
      #pragma unroll
      for (int d = 1; d < 64; d <<= 1) {
        float ov = __shfl_xor(bv, d);
        int   oi = __shfl_xor(bi, d);
        if (ov > bv || (ov == bv && oi < bi)) { bv = ov; bi = oi; }
      }
      if (lane == 0) {
        tokS[mm * 16 + wave] = bi;
        __hip_atomic_store(wsi + TOKI + (g * 2 + mm) * 16 + wave, bi,
                           __ATOMIC_RELAXED, __HIP_MEMORY_SCOPE_AGENT);
      }
    }
    __syncthreads();   // drains token stores
    if (tid == 0) {
      __hip_atomic_store(flg_own, base + 4, __ATOMIC_RELAXED, __HIP_MEMORY_SCOPE_AGENT);
      for (int it = 0; it < 20000000; ++it) {
        if (__hip_atomic_load(flg_oth, __ATOMIC_RELAXED, __HIP_MEMORY_SCOPE_AGENT) >= base + 4) break;
        __builtin_amdgcn_s_sleep(2);
      }
    }
    __syncthreads();
    if (tid < 16)
      tokS[(mm ^ 1) * 16 + tid] =
          __hip_atomic_load(wsi + TOKI + (g * 2 + (mm ^ 1)) * 16 + tid,
                            __ATOMIC_RELAXED, __HIP_MEMORY_SCOPE_AGENT);
    __syncthreads();
    #pragma unroll
    for (int k2 = 0; k2 < 2; ++k2) {
      int rr = wave * 2 + k2;
      int tk = tokS[rr];
      float ev = emb[(size_t)tk * 64 + lane];
      int rz = rr >> 4, mz = rr & 15, off = FOFF(mz, lane);
      bf16 hi = (bf16)ev;
      xzS[0][rz][off] = hi;
      xzS[1][rz][off] = (bf16)(ev - (float)hi);
    }
    __syncthreads();
  }
}

extern "C" void kernel_launch(void* const* d_in, const int* in_sizes, int n_in,
                              void* d_out, int out_size, void* d_ws, size_t ws_size,
                              hipStream_t stream) {
  bf16* wsb = (bf16*)d_ws;
  int*  wsi = (int*)d_ws;
  u64*  wsu = (u64*)d_ws;

  flg_init<<<16, 256, 0, stream>>>(wsi);

  // gate matrices: pair-split packing
  pack2p<<<24, 256, 0, stream>>>((const float*)d_in[6],  wsb + O_L0, 2, 10, 0, 64);
  pack2p<<<96, 256, 0, stream>>>((const float*)d_in[7],  wsb + O_L0, 8, 10, 2, 256);
  pack2p<<<96, 256, 0, stream>>>((const float*)d_in[10], wsb + O_L1, 8, 16, 0, 256);
  pack2p<<<96, 256, 0, stream>>>((const float*)d_in[11], wsb + O_L1, 8, 16, 8, 256);
  pack2p<<<96, 256, 0, stream>>>((const float*)d_in[14], wsb + O_L2, 8, 16, 0, 256);
  pack2p<<<96, 256, 0, stream>>>((const float*)d_in[15], wsb + O_L2, 8, 16, 8, 256);
  // z2h / outw: simple packing (read in full by both members)
  pack2s<<<48, 256, 0, stream>>>((const float*)d_in[2], wsb + O_Z2H, 48, 4, 4, 0, 128);
  pack2s<<<8,  256, 0, stream>>>((const float*)d_in[4], wsb + O_OUTW, 4, 8, 8, 0, 256);

  moldec_mfma<<<NBLK, 1024, 0, stream>>>(
      (const float*)d_in[0],  (const float*)d_in[1],
      (const float*)d_in[3],  (const float*)d_in[5],
      (const float*)d_in[8],  (const float*)d_in[9],
      (const float*)d_in[12], (const float*)d_in[13],
      (const float*)d_in[16], (const float*)d_in[17],
      wsb, wsi, wsu, (float*)d_out);
}

// Round 15
// 20136.122 us; speedup vs baseline: 1.0049x; 1.0049x over previous
//
#include <hip/hip_runtime.h>
#include <hip/hip_bf16.h>

typedef __bf16 bf16;
typedef __bf16 bf16x8 __attribute__((ext_vector_type(8)));
typedef float  f32x4  __attribute__((ext_vector_type(4)));

#define MFMA16(a,b,c) __builtin_amdgcn_mfma_f32_16x16x32_bf16((a),(b),(c),0,0,0)
#define NSTEP 119
#define BM 32
#define NBLK 128

// ws offsets (bf16 elems). Fused-K groups; frag (c,kt) = 1024 bf16 [hi512|lo512].
#define O_L0   0u         // 48 tiles x KTg=10 (kt0-1 wih0, kt2-9 whh0)
#define O_L1   491520u    // 48 x 16 (kt0-7 wih1, kt8-15 whh1)
#define O_L2   1277952u   // 48 x 16
#define O_Z2H  2064384u   // 48 x 4
#define O_OUTW 2260992u   // 4 x 8

// A-frag offset for (row m in 0..15, col k): lane = m+16*((k>>3)&3), elem k&7
#define FOFF(m,k) (((k)>>5)*512 + ((m) + 16*(((k)>>3)&3))*8 + ((k)&7))

__device__ __forceinline__ f32x4 splat4(float v){ f32x4 r={v,v,v,v}; return r; }

__device__ __forceinline__ unsigned pk2(float a, float b){
  union { __bf16 h[2]; unsigned u; } x;
  x.h[0] = (bf16)a; x.h[1] = (bf16)b; return x.u;
}
__device__ __forceinline__ float upk(unsigned u, int i){
  union { __bf16 h[2]; unsigned u; } x;
  x.u = u; return (float)x.h[i];
}
__device__ __forceinline__ float sigf(float x){ return 1.f/(1.f+expf(-x)); }

// fp32 W[Rt*16][K] -> fused-group MFMA B-frags, hi/lo split.
// dst frag index = c*KTg + ktoff + ktm.
__global__ void pack2(const float* __restrict__ src, bf16* __restrict__ dst,
                      int Rt, int KTm, int KTg, int ktoff, int K) {
  int idx = blockIdx.x * 256 + threadIdx.x;
  if (idx >= Rt * KTm * 64) return;
  int lane = idx & 63, fi = idx >> 6;
  int r15 = lane & 15, q = lane >> 4;
  int c = fi / KTm, ktm = fi - c * KTm;
  const float* s = src + (size_t)(c * 16 + r15) * K + ktm * 32 + q * 8;
  bf16* d = dst + (size_t)(c * KTg + ktoff + ktm) * 1024 + lane * 8;
  #pragma unroll
  for (int e = 0; e < 8; ++e) {
    float v = s[e];
    bf16 hi = (bf16)v;
    d[e] = hi;
    d[e + 512] = (bf16)(v - (float)hi);
  }
}

// asm-pinned 16B load (volatile order preserved vs the waitcnt asms).
__device__ __forceinline__ void gl16(bf16x8& d, const bf16* p) {
  asm volatile("global_load_dwordx4 %0, %1, off" : "=v"(d) : "v"(p));
}

// Fused-K GEMM: gates += [Ai (kt<KTI) | Ah (kt>=KTI)] @ Wfused^T.
// r,z tiles accumulate into aRZ; n-tile routes to aI (input part) / aH (h part).
// Ring-3 B-prefetch (2-deep): steady state 18 loads in flight, counted
// vmcnt(12/6/0) ladder, sched_barrier after waits (rule #18).
template<int KTI, int KT, int KTG>
__device__ __forceinline__ void gemmF(
    f32x4 (&aRZ)[2][2], f32x4 (&aI)[2], f32x4 (&aH)[2],
    const bf16* __restrict__ Ai0, const bf16* __restrict__ Ai1, const int SAI,
    const bf16* __restrict__ Ah0, const bf16* __restrict__ Ah1, const int SAH,
    const bf16* __restrict__ BG, const int wv, const int lane)
{
  const size_t TS = (size_t)16 * KTG * 1024;   // col-tile stride (16 tiles apart)
  const bf16* bp = BG + (size_t)wv * KTG * 1024 + lane * 8;
  bf16x8 rb[3][3][2];
  asm volatile("s_waitcnt vmcnt(0)" ::: "memory");   // drain stray vmem ops
  __builtin_amdgcn_sched_barrier(0);
  #pragma unroll
  for (int p = 0; p < 2; ++p) {
    if (p < KT) {
      #pragma unroll
      for (int t = 0; t < 3; ++t) {
        gl16(rb[p][t][0], bp + t * TS + (size_t)p * 1024);
        gl16(rb[p][t][1], bp + t * TS + (size_t)p * 1024 + 512);
      }
    }
  }
  #pragma unroll
  for (int kt = 0; kt < KT; ++kt) {
    const int s = kt % 3;
    if (kt + 2 < KT) {
      #pragma unroll
      for (int t = 0; t < 3; ++t) {
        gl16(rb[(kt + 2) % 3][t][0], bp + t * TS + (size_t)(kt + 2) * 1024);
        gl16(rb[(kt + 2) % 3][t][1], bp + t * TS + (size_t)(kt + 2) * 1024 + 512);
      }
      asm volatile("s_waitcnt vmcnt(12)" ::: "memory");
    } else if (kt + 1 < KT) {
      asm volatile("s_waitcnt vmcnt(6)" ::: "memory");
    } else {
      asm volatile("s_waitcnt vmcnt(0)" ::: "memory");
    }
    __builtin_amdgcn_sched_barrier(0);
    const bf16* A0 = (kt < KTI) ? Ai0 : Ah0;
    const bf16* A1 = (kt < KTI) ? Ai1 : Ah1;
    const int SA   = (kt < KTI) ? SAI : SAH;
    const int ka   = (kt < KTI) ? kt : (kt - KTI);
    #pragma unroll
    for (int rt = 0; rt < 2; ++rt) {
      bf16x8 a0 = *(const bf16x8*)(A0 + rt * SA + ka * 512 + lane * 8);
      bf16x8 a1 = *(const bf16x8*)(A1 + rt * SA + ka * 512 + lane * 8);
      aRZ[rt][0] = MFMA16(a0, rb[s][0][0], aRZ[rt][0]);
      aRZ[rt][0] = MFMA16(a1, rb[s][0][0], aRZ[rt][0]);
      aRZ[rt][0] = MFMA16(a0, rb[s][0][1], aRZ[rt][0]);
      aRZ[rt][1] = MFMA16(a0, rb[s][1][0], aRZ[rt][1]);
      aRZ[rt][1] = MFMA16(a1, rb[s][1][0], aRZ[rt][1]);
      aRZ[rt][1] = MFMA16(a0, rb[s][1][1], aRZ[rt][1]);
      f32x4& an = (kt < KTI) ? aI[rt] : aH[rt];
      an = MFMA16(a0, rb[s][2][0], an);
      an = MFMA16(a1, rb[s][2][0], an);
      an = MFMA16(a0, rb[s][2][1], an);
    }
  }
}

// GRU update; h comps 0/1 in LDS (frag-major), comp2 packed bf16-pairs in regs.
__device__ __forceinline__ void updF(
    bf16* __restrict__ h0, bf16* __restrict__ h1,
    const f32x4 (&aRZ)[2][2], const f32x4 (&aI)[2], const f32x4 (&aH)[2],
    unsigned (&c2p)[2][2], const int q, const int j)
{
  #pragma unroll
  for (int rt = 0; rt < 2; ++rt) {
    float c2v[4] = { upk(c2p[rt][0],0), upk(c2p[rt][0],1),
                     upk(c2p[rt][1],0), upk(c2p[rt][1],1) };
    #pragma unroll
    for (int r = 0; r < 4; ++r) {
      const int off = rt * 4096 + FOFF(q*4+r, j);
      float rg = sigf(aRZ[rt][0][r]);
      float zg = sigf(aRZ[rt][1][r]);
      float ng = tanhf(aI[rt][r] + rg * aH[rt][r]);
      float hp = (float)h0[off] + (float)h1[off] + c2v[r];
      float hv = (1.f - zg) * ng + zg * hp;
      bf16 d0 = (bf16)hv; float r1 = hv - (float)d0;
      bf16 d1 = (bf16)r1; c2v[r] = r1 - (float)d1;
      h0[off] = d0; h1[off] = d1;
    }
    c2p[rt][0] = pk2(c2v[0], c2v[1]);
    c2p[rt][1] = pk2(c2v[2], c2v[3]);
  }
}

__device__ __forceinline__ void setbias(const float* __restrict__ bSl, int j,
    f32x4 (&aRZ)[2][2], f32x4 (&aI)[2], f32x4 (&aH)[2]) {
  float br  = bSl[j] + bSl[768 + j];
  float bz  = bSl[256 + j] + bSl[768 + 256 + j];
  float bni = bSl[512 + j];
  float bnh = bSl[768 + 512 + j];
  #pragma unroll
  for (int rt = 0; rt < 2; ++rt) {
    aRZ[rt][0] = splat4(br); aRZ[rt][1] = splat4(bz);
    aI[rt] = splat4(bni);    aH[rt] = splat4(bnh);
  }
}

__global__ __launch_bounds__(1024)
void moldec_mfma(const float* __restrict__ z, const float* __restrict__ emb,
                 const float* __restrict__ z2h_b, const float* __restrict__ out_b,
                 const float* __restrict__ bih0, const float* __restrict__ bhh0,
                 const float* __restrict__ bih1, const float* __restrict__ bhh1,
                 const float* __restrict__ bih2, const float* __restrict__ bhh2,
                 const bf16* __restrict__ wsb, float* __restrict__ out)
{
  __shared__ __align__(16) bf16 hS[3][2][2][4096];  // [layer][comp][rt][8kt*512]
  __shared__ __align__(16) bf16 xzS[2][2][2048];    // [comp][rt][4kt*512]
  __shared__ float logS2[2][32][66];
  __shared__ float bS[3 * 1536];                    // [l][ih/hh][768]
  __shared__ float obS[64];

  const int tid = threadIdx.x, wave = tid >> 6, lane = tid & 63;
  const int q = lane >> 4, r15 = lane & 15;
  const int b0 = blockIdx.x * BM;
  const int wv = wave;
  const int j = wv * 16 + r15;       // owned neuron col (per layer)

  // ---- biases -> LDS ----
  {
    const float* bp_[6] = {bih0, bhh0, bih1, bhh1, bih2, bhh2};
    for (int i = tid; i < 4608; i += 1024) {
      int l = i / 1536, w2 = (i % 1536) / 768, g = i % 768;
      bS[i] = bp_[l * 2 + w2][g];
    }
    if (tid < 64) obS[tid] = out_b[tid];
  }

  // ---- stage z (32 rows x 128) into 2-comp frags ----
  {
    const int m = tid >> 5, c4 = (tid & 31) * 4;
    const int rt = m >> 4, mm = m & 15;
    float4 v = *(const float4*)(z + (size_t)(b0 + m) * 128 + c4);
    const float vv[4] = {v.x, v.y, v.z, v.w};
    #pragma unroll
    for (int e = 0; e < 4; ++e) {
      int off = FOFF(mm, c4 + e);
      bf16 hi = (bf16)vv[e];
      xzS[0][rt][off] = hi;
      xzS[1][rt][off] = (bf16)(vv[e] - (float)hi);
    }
  }
  __syncthreads();

  unsigned c2p[3][2][2];   // h comp2, packed bf16 pairs [layer][rt][rowpair]

  // ---- h0 = tanh(z @ z2h_w.T + b) ----
  {
    f32x4 acc[2][3];
    #pragma unroll
    for (int rt = 0; rt < 2; ++rt)
      #pragma unroll
      for (int t = 0; t < 3; ++t) acc[rt][t] = splat4(z2h_b[t * 256 + j]);
    #pragma unroll
    for (int kt = 0; kt < 4; ++kt) {
      #pragma unroll
      for (int rt = 0; rt < 2; ++rt) {
        bf16x8 a0 = *(const bf16x8*)(&xzS[0][rt][kt * 512 + lane * 8]);
        bf16x8 a1 = *(const bf16x8*)(&xzS[1][rt][kt * 512 + lane * 8]);
        #pragma unroll
        for (int t = 0; t < 3; ++t) {
          const bf16* bb = wsb + O_Z2H + (size_t)((wv + t * 16) * 4 + kt) * 1024 + lane * 8;
          bf16x8 b0 = *(const bf16x8*)bb;
          bf16x8 b1 = *(const bf16x8*)(bb + 512);
          acc[rt][t] = MFMA16(a0, b0, acc[rt][t]);
          acc[rt][t] = MFMA16(a1, b0, acc[rt][t]);
          acc[rt][t] = MFMA16(a0, b1, acc[rt][t]);
        }
      }
    }
    #pragma unroll
    for (int t = 0; t < 3; ++t)
      #pragma unroll
      for (int rt = 0; rt < 2; ++rt) {
        float c2v[4];
        #pragma unroll
        for (int r = 0; r < 4; ++r) {
          int off = rt * 4096 + FOFF(q * 4 + r, j);
          float hv = tanhf(acc[rt][t][r]);
          bf16 d0 = (bf16)hv; float r1 = hv - (float)d0;
          bf16 d1 = (bf16)r1; c2v[r] = r1 - (float)d1;
          (&hS[t][0][0][0])[off] = d0;
          (&hS[t][1][0][0])[off] = d1;
        }
        c2p[t][rt][0] = pk2(c2v[0], c2v[1]);
        c2p[t][rt][1] = pk2(c2v[2], c2v[3]);
      }
  }
  // ---- stage x = emb[1] for rows 2w, 2w+1 ----
  {
    float ev = emb[64 + lane];
    bf16 hi = (bf16)ev;
    bf16 lo = (bf16)(ev - (float)hi);
    #pragma unroll
    for (int k2 = 0; k2 < 2; ++k2) {
      int rr = wave * 2 + k2;
      int rt = rr >> 4, mm = rr & 15, off = FOFF(mm, lane);
      xzS[0][rt][off] = hi;
      xzS[1][rt][off] = lo;
    }
  }
  __syncthreads();

  for (int step = 0; step < NSTEP; ++step) {
    f32x4 aRZ[2][2], aI[2], aH[2];

    // ---- P0: layer 0, fused [x | h0] (KT = 2+8) ----
    setbias(bS, j, aRZ, aI, aH);
    gemmF<2, 10, 10>(aRZ, aI, aH,
                     &xzS[0][0][0], &xzS[1][0][0], 2048,
                     &hS[0][0][0][0], &hS[0][1][0][0], 4096,
                     wsb + O_L0, wv, lane);
    __syncthreads();
    updF(&hS[0][0][0][0], &hS[0][1][0][0], aRZ, aI, aH, c2p[0], q, j);
    __syncthreads();

    // ---- P1: layer 1, fused [h0' | h1] (KT = 8+8) ----
    setbias(bS + 1536, j, aRZ, aI, aH);
    gemmF<8, 16, 16>(aRZ, aI, aH,
                     &hS[0][0][0][0], &hS[0][1][0][0], 4096,
                     &hS[1][0][0][0], &hS[1][1][0][0], 4096,
                     wsb + O_L1, wv, lane);
    __syncthreads();
    updF(&hS[1][0][0][0], &hS[1][1][0][0], aRZ, aI, aH, c2p[1], q, j);
    __syncthreads();

    // ---- P2: layer 2, fused [h1' | h2] ----
    setbias(bS + 3072, j, aRZ, aI, aH);
    gemmF<8, 16, 16>(aRZ, aI, aH,
                     &hS[1][0][0][0], &hS[1][1][0][0], 4096,
                     &hS[2][0][0][0], &hS[2][1][0][0], 4096,
                     wsb + O_L2, wv, lane);
    __syncthreads();
    updF(&hS[2][0][0][0], &hS[2][1][0][0], aRZ, aI, aH, c2p[2], q, j);
    __syncthreads();

    // ---- logits: wave = (rt, tt, kh) 2x4x2 ----
    {
      const int rt = wave >> 3, tt = (wave >> 1) & 3, kh = wave & 1;
      f32x4 acc = kh ? splat4(0.f) : splat4(obS[tt * 16 + r15]);
      #pragma unroll
      for (int kt = 0; kt < 4; ++kt) {
        int kg = kh * 4 + kt;
        bf16x8 a0 = *(const bf16x8*)(&hS[2][0][rt][kg * 512 + lane * 8]);
        bf16x8 a1 = *(const bf16x8*)(&hS[2][1][rt][kg * 512 + lane * 8]);
        const bf16* bb = wsb + O_OUTW + (size_t)(tt * 8 + kg) * 1024 + lane * 8;
        bf16x8 b0 = *(const bf16x8*)bb;
        bf16x8 b1 = *(const bf16x8*)(bb + 512);
        acc = MFMA16(a0, b0, acc);
        acc = MFMA16(a1, b0, acc);
        acc = MFMA16(a0, b1, acc);
      }
      #pragma unroll
      for (int r = 0; r < 4; ++r)
        logS2[kh][rt * 16 + q * 4 + r][tt * 16 + r15] = acc[r];
    }
    __syncthreads();

    // ---- store + argmax (first-max) + stage next x; wave owns rows 2w,2w+1 ----
    #pragma unroll
    for (int k2 = 0; k2 < 2; ++k2) {
      int rr = wave * 2 + k2;
      float v = logS2[0][rr][lane] + logS2[1][rr][lane];
      out[((size_t)(b0 + rr) * NSTEP + step) * 64 + lane] = v;
      float bv = v; int bi = lane;
      #pragma unroll
      for (int d = 1; d < 64; d <<= 1) {
        float ov = __shfl_xor(bv, d);
        int   oi = __shfl_xor(bi, d);
        if (ov > bv || (ov == bv && oi < bi)) { bv = ov; bi = oi; }
      }
      float ev = emb[(size_t)bi * 64 + lane];
      int rt = rr >> 4, mm = rr & 15, off = FOFF(mm, lane);
      bf16 hi = (bf16)ev;
      xzS[0][rt][off] = hi;
      xzS[1][rt][off] = (bf16)(ev - (float)hi);
    }
    __syncthreads();
  }
}

extern "C" void kernel_launch(void* const* d_in, const int* in_sizes, int n_in,
                              void* d_out, int out_size, void* d_ws, size_t ws_size,
                              hipStream_t stream) {
  bf16* wsb = (bf16*)d_ws;

  pack2<<<24, 256, 0, stream>>>((const float*)d_in[6],  wsb + O_L0,  48, 2, 10, 0, 64);
  pack2<<<96, 256, 0, stream>>>((const float*)d_in[7],  wsb + O_L0,  48, 8, 10, 2, 256);
  pack2<<<96, 256, 0, stream>>>((const float*)d_in[10], wsb + O_L1,  48, 8, 16, 0, 256);
  pack2<<<96, 256, 0, stream>>>((const float*)d_in[11], wsb + O_L1,  48, 8, 16, 8, 256);
  pack2<<<96, 256, 0, stream>>>((const float*)d_in[14], wsb + O_L2,  48, 8, 16, 0, 256);
  pack2<<<96, 256, 0, stream>>>((const float*)d_in[15], wsb + O_L2,  48, 8, 16, 8, 256);
  pack2<<<48, 256, 0, stream>>>((const float*)d_in[2],  wsb + O_Z2H, 48, 4, 4,  0, 128);
  pack2<<<8,  256, 0, stream>>>((const float*)d_in[4],  wsb + O_OUTW, 4, 8, 8,  0, 256);

  moldec_mfma<<<NBLK, 1024, 0, stream>>>(
      (const float*)d_in[0],  (const float*)d_in[1],
      (const float*)d_in[3],  (const float*)d_in[5],
      (const float*)d_in[8],  (const float*)d_in[9],
      (const float*)d_in[12], (const float*)d_in[13],
      (const float*)d_in[16], (const float*)d_in[17],
      wsb, (float*)d_out);
}

// Round 16
// 6656.124 us; speedup vs baseline: 3.0400x; 3.0252x over previous
//
#include <hip/hip_runtime.h>
#include <hip/hip_bf16.h>

typedef __bf16 bf16;
typedef __bf16 bf16x8 __attribute__((ext_vector_type(8)));
typedef float  f32x4  __attribute__((ext_vector_type(4)));

#define MFMA16(a,b,c) __builtin_amdgcn_mfma_f32_16x16x32_bf16((a),(b),(c),0,0,0)
#define NSTEP 119

// weight frags (bf16 elems); frag (c,kt) = 1024 bf16 [hi512|lo512]
#define O_L0   0u         // 48 tiles x KTg=10 (kt0-1 wih0, kt2-9 whh0)
#define O_L1   491520u    // 48 x 16 (kt0-7 wih1, kt8-15 whh1)
#define O_L2   1277952u   // 48 x 16
#define O_Z2H  2064384u   // 48 x 4
#define O_OUTW 2260992u   // 4 x 8
// fp32 h-state (float idx; byte 4587520 onward) + tokens
#define FH0 1146880u
#define FH1 2195456u
#define FH2 3244032u
#define FTOK 4292608u     // int idx: 4096 tokens

#define FOFF(m,k) (((k)>>5)*512 + ((m) + 16*(((k)>>3)&3))*8 + ((k)&7))

__device__ __forceinline__ f32x4 splat4(float v){ f32x4 r={v,v,v,v}; return r; }
__device__ __forceinline__ float sigf(float x){ return 1.f/(1.f+expf(-x)); }

// fp32 W[Rt*16][K] -> MFMA B-frags, hi/lo split; frag idx = c*KTg + ktoff + ktm
__global__ void pack2(const float* __restrict__ src, bf16* __restrict__ dst,
                      int Rt, int KTm, int KTg, int ktoff, int K) {
  int idx = blockIdx.x * 256 + threadIdx.x;
  if (idx >= Rt * KTm * 64) return;
  int lane = idx & 63, fi = idx >> 6;
  int r15 = lane & 15, q = lane >> 4;
  int c = fi / KTm, ktm = fi - c * KTm;
  const float* s = src + (size_t)(c * 16 + r15) * K + ktm * 32 + q * 8;
  bf16* d = dst + (size_t)(c * KTg + ktoff + ktm) * 1024 + lane * 8;
  #pragma unroll
  for (int e = 0; e < 8; ++e) {
    float v = s[e];
    bf16 hi = (bf16)v;
    d[e] = hi;
    d[e + 512] = (bf16)(v - (float)hi);
  }
}

// init: h[0..2] = tanh(z @ z2h_w^T + b) -> fp32 state; tokens = 1
__global__ __launch_bounds__(512)
void kinit(const float* __restrict__ z, const float* __restrict__ z2h_b,
           const bf16* __restrict__ wsb, float* __restrict__ wsf,
           int* __restrict__ wsi)
{
  __shared__ __align__(16) bf16 zF[2][2048];
  const int tid = threadIdx.x, wv = tid >> 6, lane = tid & 63;
  const int q = lane >> 4, r15 = lane & 15;
  const int b0 = blockIdx.x * 16;
  {
    const int m = tid >> 5, c4 = (tid & 31) * 4;
    float4 v = *(const float4*)(z + (size_t)(b0 + m) * 128 + c4);
    const float vv[4] = {v.x, v.y, v.z, v.w};
    #pragma unroll
    for (int e = 0; e < 4; ++e) {
      int off = FOFF(m, c4 + e);
      bf16 hi = (bf16)vv[e];
      zF[0][off] = hi;
      zF[1][off] = (bf16)(vv[e] - (float)hi);
    }
    if (tid < 16) wsi[FTOK + b0 + tid] = 1;
  }
  __syncthreads();
  f32x4 acc[6];
  #pragma unroll
  for (int t = 0; t < 6; ++t) acc[t] = splat4(z2h_b[(wv * 6 + t) * 16 + r15]);
  #pragma unroll
  for (int kt = 0; kt < 4; ++kt) {
    bf16x8 a0 = *(const bf16x8*)(&zF[0][kt * 512 + lane * 8]);
    bf16x8 a1 = *(const bf16x8*)(&zF[1][kt * 512 + lane * 8]);
    #pragma unroll
    for (int t = 0; t < 6; ++t) {
      const bf16* bb = wsb + O_Z2H + (size_t)((wv * 6 + t) * 4 + kt) * 1024 + lane * 8;
      bf16x8 b0 = *(const bf16x8*)bb;
      bf16x8 b1 = *(const bf16x8*)(bb + 512);
      acc[t] = MFMA16(a0, b0, acc[t]);
      acc[t] = MFMA16(a1, b0, acc[t]);
      acc[t] = MFMA16(a0, b1, acc[t]);
    }
  }
  #pragma unroll
  for (int t = 0; t < 6; ++t) {
    const int col = (wv * 6 + t) * 16 + r15;
    const int lay = col >> 8, j = col & 255;
    float* H = wsf + (lay == 0 ? FH0 : lay == 1 ? FH1 : FH2);
    #pragma unroll
    for (int r = 0; r < 4; ++r)
      H[(size_t)(b0 + q * 4 + r) * 256 + j] = tanhf(acc[t][r]);
  }
}

__device__ __forceinline__ void gl16(bf16x8& d, const bf16* p) {
  asm volatile("global_load_dwordx4 %0, %1, off" : "=v"(d) : "v"(p));
}

// One GRU layer for 16 batch rows; L2 fuses logits+argmax+token.
// 8 waves; wave owns j-tiles {wv*2, wv*2+1} x 3 gates (c = g3*16 + wv*2 + jt).
template<int L, int KTI, int KTG>
__global__ __launch_bounds__(512)
void klayer(const float* __restrict__ emb,
            const float* __restrict__ bih, const float* __restrict__ bhh,
            const float* __restrict__ out_b,
            const bf16* __restrict__ wsb, float* __restrict__ wsf,
            int* __restrict__ wsi, float* __restrict__ out, int step)
{
  constexpr int KT = KTI + 8;
  __shared__ __align__(16) bf16 AiF[2][KTI * 512];
  __shared__ __align__(16) bf16 AhF[2][8 * 512];
  __shared__ float logS2[2][16][68];
  const int tid = threadIdx.x, wv = tid >> 6, lane = tid & 63;
  const int q = lane >> 4, r15 = lane & 15;
  const int b0 = blockIdx.x * 16;
  const size_t WB = (L == 0) ? O_L0 : (L == 1) ? O_L1 : O_L2;
  const unsigned FHcur = (L == 0) ? FH0 : (L == 1) ? FH1 : FH2;

  // ---- stage Ain ----
  if constexpr (L == 0) {
    if (tid < 256) {
      const int m = tid >> 4, e4 = (tid & 15) * 4;
      const int tk = wsi[FTOK + b0 + m];
      float4 v = *(const float4*)(emb + (size_t)tk * 64 + e4);
      const float vv[4] = {v.x, v.y, v.z, v.w};
      #pragma unroll
      for (int e = 0; e < 4; ++e) {
        int off = FOFF(m, e4 + e);
        bf16 hi = (bf16)vv[e];
        AiF[0][off] = hi;
        AiF[1][off] = (bf16)(vv[e] - (float)hi);
      }
    }
  } else {
    const unsigned FHin = (L == 1) ? FH0 : FH1;
    const int m = tid >> 5, c8 = (tid & 31) * 8;
    float4 v0 = *(const float4*)(wsf + FHin + (size_t)(b0 + m) * 256 + c8);
    float4 v1 = *(const float4*)(wsf + FHin + (size_t)(b0 + m) * 256 + c8 + 4);
    const float vv[8] = {v0.x, v0.y, v0.z, v0.w, v1.x, v1.y, v1.z, v1.w};
    #pragma unroll
    for (int e = 0; e < 8; ++e) {
      int off = FOFF(m, c8 + e);
      bf16 hi = (bf16)vv[e];
      AiF[0][off] = hi;
      AiF[1][off] = (bf16)(vv[e] - (float)hi);
    }
  }
  // ---- stage Ah from current-layer state ----
  {
    const int m = tid >> 5, c8 = (tid & 31) * 8;
    float4 v0 = *(const float4*)(wsf + FHcur + (size_t)(b0 + m) * 256 + c8);
    float4 v1 = *(const float4*)(wsf + FHcur + (size_t)(b0 + m) * 256 + c8 + 4);
    const float vv[8] = {v0.x, v0.y, v0.z, v0.w, v1.x, v1.y, v1.z, v1.w};
    #pragma unroll
    for (int e = 0; e < 8; ++e) {
      int off = FOFF(m, c8 + e);
      bf16 hi = (bf16)vv[e];
      AhF[0][off] = hi;
      AhF[1][off] = (bf16)(vv[e] - (float)hi);
    }
  }
  __syncthreads();

  // ---- fused gate GEMM, asm ring-2, counted vmcnt ----
  f32x4 aR[2], aZ[2], aNI[2], aNH[2];
  #pragma unroll
  for (int jt = 0; jt < 2; ++jt) {
    aR[jt] = splat4(0.f); aZ[jt] = splat4(0.f);
    aNI[jt] = splat4(0.f); aNH[jt] = splat4(0.f);
  }
  const bf16* bp[6];
  #pragma unroll
  for (int g3 = 0; g3 < 3; ++g3)
    #pragma unroll
    for (int jt = 0; jt < 2; ++jt)
      bp[g3 * 2 + jt] = wsb + WB + (size_t)((g3 * 16 + wv * 2 + jt) * KTG) * 1024 + lane * 8;

  bf16x8 rb[2][6][2];
  asm volatile("s_waitcnt vmcnt(0)" ::: "memory");
  __builtin_amdgcn_sched_barrier(0);
  #pragma unroll
  for (int t = 0; t < 6; ++t) {
    gl16(rb[0][t][0], bp[t]);
    gl16(rb[0][t][1], bp[t] + 512);
  }
  #pragma unroll
  for (int kt = 0; kt < KT; ++kt) {
    const int s = kt & 1;
    if (kt + 1 < KT) {
      #pragma unroll
      for (int t = 0; t < 6; ++t) {
        gl16(rb[s ^ 1][t][0], bp[t] + (size_t)(kt + 1) * 1024);
        gl16(rb[s ^ 1][t][1], bp[t] + (size_t)(kt + 1) * 1024 + 512);
      }
      asm volatile("s_waitcnt vmcnt(12)" ::: "memory");
    } else {
      asm volatile("s_waitcnt vmcnt(0)" ::: "memory");
    }
    __builtin_amdgcn_sched_barrier(0);
    const bf16* A0;
    const bf16* A1;
    if (kt < KTI) { A0 = &AiF[0][kt * 512]; A1 = &AiF[1][kt * 512]; }
    else          { A0 = &AhF[0][(kt - KTI) * 512]; A1 = &AhF[1][(kt - KTI) * 512]; }
    bf16x8 a0 = *(const bf16x8*)(A0 + lane * 8);
    bf16x8 a1 = *(const bf16x8*)(A1 + lane * 8);
    #pragma unroll
    for (int jt = 0; jt < 2; ++jt) {
      aR[jt] = MFMA16(a0, rb[s][jt][0], aR[jt]);
      aR[jt] = MFMA16(a1, rb[s][jt][0], aR[jt]);
      aR[jt] = MFMA16(a0, rb[s][jt][1], aR[jt]);
      aZ[jt] = MFMA16(a0, rb[s][2 + jt][0], aZ[jt]);
      aZ[jt] = MFMA16(a1, rb[s][2 + jt][0], aZ[jt]);
      aZ[jt] = MFMA16(a0, rb[s][2 + jt][1], aZ[jt]);
      f32x4& aN = (kt < KTI) ? aNI[jt] : aNH[jt];
      aN = MFMA16(a0, rb[s][4 + jt][0], aN);
      aN = MFMA16(a1, rb[s][4 + jt][0], aN);
      aN = MFMA16(a0, rb[s][4 + jt][1], aN);
    }
  }

  // ---- GRU update (h fp32 authoritative in global) ----
  float hnew[2][4];
  #pragma unroll
  for (int jt = 0; jt < 2; ++jt) {
    const int j = wv * 32 + jt * 16 + r15;
    const float brz = bih[j] + bhh[j];
    const float bz  = bih[256 + j] + bhh[256 + j];
    const float bni = bih[512 + j];
    const float bnh = bhh[512 + j];
    #pragma unroll
    for (int r = 0; r < 4; ++r) {
      const int m = q * 4 + r;
      float rg = sigf(aR[jt][r] + brz);
      float zg = sigf(aZ[jt][r] + bz);
      float ng = tanhf(aNI[jt][r] + bni + rg * (aNH[jt][r] + bnh));
      float hp = wsf[FHcur + (size_t)(b0 + m) * 256 + j];
      float hv = (1.f - zg) * ng + zg * hp;
      wsf[FHcur + (size_t)(b0 + m) * 256 + j] = hv;
      hnew[jt][r] = hv;
    }
  }

  if constexpr (L == 2) {
    __syncthreads();   // all waves done reading AhF
    #pragma unroll
    for (int jt = 0; jt < 2; ++jt) {
      const int j = wv * 32 + jt * 16 + r15;
      #pragma unroll
      for (int r = 0; r < 4; ++r) {
        const int off = FOFF(q * 4 + r, j);
        bf16 hi = (bf16)hnew[jt][r];
        AhF[0][off] = hi;
        AhF[1][off] = (bf16)(hnew[jt][r] - (float)hi);
      }
    }
    __syncthreads();
    // logits: wave = (ks, tt)
    {
      const int ks = wv >> 2, tt = wv & 3;
      f32x4 acc = ks ? splat4(0.f) : splat4(out_b[tt * 16 + r15]);
      #pragma unroll
      for (int kt2 = 0; kt2 < 4; ++kt2) {
        const int kg = ks * 4 + kt2;
        bf16x8 a0 = *(const bf16x8*)(&AhF[0][kg * 512 + lane * 8]);
        bf16x8 a1 = *(const bf16x8*)(&AhF[1][kg * 512 + lane * 8]);
        const bf16* bb = wsb + O_OUTW + (size_t)(tt * 8 + kg) * 1024 + lane * 8;
        bf16x8 b0 = *(const bf16x8*)bb;
        bf16x8 b1 = *(const bf16x8*)(bb + 512);
        acc = MFMA16(a0, b0, acc);
        acc = MFMA16(a1, b0, acc);
        acc = MFMA16(a0, b1, acc);
      }
      #pragma unroll
      for (int r = 0; r < 4; ++r)
        logS2[ks][q * 4 + r][tt * 16 + r15] = acc[r];
    }
    __syncthreads();
    // store + argmax (first-max) + token; wave owns rows 2wv, 2wv+1
    #pragma unroll
    for (int k2 = 0; k2 < 2; ++k2) {
      const int rr = wv * 2 + k2;
      float v = logS2[0][rr][lane] + logS2[1][rr][lane];
      out[((size_t)(b0 + rr) * NSTEP + step) * 64 + lane] = v;
      float bv = v; int bi = lane;
      #pragma unroll
      for (int d = 1; d < 64; d <<= 1) {
        float ov = __shfl_xor(bv, d);
        int   oi = __shfl_xor(bi, d);
        if (ov > bv || (ov == bv && oi < bi)) { bv = ov; bi = oi; }
      }
      if (lane == 0) wsi[FTOK + b0 + rr] = bi;
    }
  }
}

extern "C" void kernel_launch(void* const* d_in, const int* in_sizes, int n_in,
                              void* d_out, int out_size, void* d_ws, size_t ws_size,
                              hipStream_t stream) {
  bf16*  wsb = (bf16*)d_ws;
  float* wsf = (float*)d_ws;
  int*   wsi = (int*)d_ws;
  const float* z     = (const float*)d_in[0];
  const float* emb   = (const float*)d_in[1];
  const float* z2h_b = (const float*)d_in[3];
  const float* out_b = (const float*)d_in[5];
  const float* bih0 = (const float*)d_in[8],  *bhh0 = (const float*)d_in[9];
  const float* bih1 = (const float*)d_in[12], *bhh1 = (const float*)d_in[13];
  const float* bih2 = (const float*)d_in[16], *bhh2 = (const float*)d_in[17];
  float* out = (float*)d_out;

  pack2<<<24, 256, 0, stream>>>((const float*)d_in[6],  wsb + O_L0,  48, 2, 10, 0, 64);
  pack2<<<96, 256, 0, stream>>>((const float*)d_in[7],  wsb + O_L0,  48, 8, 10, 2, 256);
  pack2<<<96, 256, 0, stream>>>((const float*)d_in[10], wsb + O_L1,  48, 8, 16, 0, 256);
  pack2<<<96, 256, 0, stream>>>((const float*)d_in[11], wsb + O_L1,  48, 8, 16, 8, 256);
  pack2<<<96, 256, 0, stream>>>((const float*)d_in[14], wsb + O_L2,  48, 8, 16, 0, 256);
  pack2<<<96, 256, 0, stream>>>((const float*)d_in[15], wsb + O_L2,  48, 8, 16, 8, 256);
  pack2<<<48, 256, 0, stream>>>((const float*)d_in[2],  wsb + O_Z2H, 48, 4, 4,  0, 128);
  pack2<<<8,  256, 0, stream>>>((const float*)d_in[4],  wsb + O_OUTW, 4, 8, 8,  0, 256);

  kinit<<<256, 512, 0, stream>>>(z, z2h_b, wsb, wsf, wsi);

  for (int t = 0; t < NSTEP; ++t) {
    klayer<0, 2, 10><<<256, 512, 0, stream>>>(emb, bih0, bhh0, out_b, wsb, wsf, wsi, out, t);
    klayer<1, 8, 16><<<256, 512, 0, stream>>>(emb, bih1, bhh1, out_b, wsb, wsf, wsi, out, t);
    klayer<2, 8, 16><<<256, 512, 0, stream>>>(emb, bih2, bhh2, out_b, wsb, wsf, wsi, out, t);
  }
}

// Round 17
// 6595.928 us; speedup vs baseline: 3.0678x; 1.0091x over previous
//
#include <hip/hip_runtime.h>
#include <hip/hip_bf16.h>

typedef __bf16 bf16;
typedef __bf16 bf16x8 __attribute__((ext_vector_type(8)));
typedef float  f32x4  __attribute__((ext_vector_type(4)));

#define MFMA16(a,b,c) __builtin_amdgcn_mfma_f32_16x16x32_bf16((a),(b),(c),0,0,0)
#define NSTEP 119

// weight frags (bf16 elems); frag (c,kt) = 1024 bf16 [hi512|lo512]
#define O_L0   0u
#define O_L1   491520u
#define O_L2   1277952u
#define O_Z2H  2064384u
#define O_OUTW 2260992u
// fp32 frag arrays (float idx): x [256rt][2kt][512]; h [256rt][8kt][512] x2 parity
#define FXF   1146880u
#define FH0A  1409024u
#define FH0B  2457600u
#define FH1A  3506176u
#define FH1B  4554752u
#define FH2A  5603328u
#define FH2B  6651904u

#define FOFF(m,k) (((k)>>5)*512 + ((m) + 16*(((k)>>3)&3))*8 + ((k)&7))

__device__ __forceinline__ f32x4 splat4(float v){ f32x4 r={v,v,v,v}; return r; }
__device__ __forceinline__ float sigf(float x){ return 1.f/(1.f+expf(-x)); }

// fp32 W[Rt*16][K] -> MFMA B-frags, hi/lo split; frag idx = c*KTg + ktoff + ktm
__global__ void pack2(const float* __restrict__ src, bf16* __restrict__ dst,
                      int Rt, int KTm, int KTg, int ktoff, int K) {
  int idx = blockIdx.x * 256 + threadIdx.x;
  if (idx >= Rt * KTm * 64) return;
  int lane = idx & 63, fi = idx >> 6;
  int r15 = lane & 15, q = lane >> 4;
  int c = fi / KTm, ktm = fi - c * KTm;
  const float* s = src + (size_t)(c * 16 + r15) * K + ktm * 32 + q * 8;
  bf16* d = dst + (size_t)(c * KTg + ktoff + ktm) * 1024 + lane * 8;
  #pragma unroll
  for (int e = 0; e < 8; ++e) {
    float v = s[e];
    bf16 hi = (bf16)v;
    d[e] = hi;
    d[e + 512] = (bf16)(v - (float)hi);
  }
}

// init: h[0..2](parity A) = tanh(z @ z2h^T + b) in fp32 frag layout; x-frags = emb[1]
__global__ __launch_bounds__(512)
void kinit(const float* __restrict__ z, const float* __restrict__ emb,
           const float* __restrict__ z2h_b, const bf16* __restrict__ wsb,
           float* __restrict__ xf, float* __restrict__ h0,
           float* __restrict__ h1, float* __restrict__ h2)
{
  __shared__ __align__(16) bf16 zF[2][2048];
  const int tid = threadIdx.x, wv = tid >> 6, lane = tid & 63;
  const int q = lane >> 4, r15 = lane & 15;
  const int rt = blockIdx.x, b0 = rt * 16;
  {
    const int m = tid >> 5, c4 = (tid & 31) * 4;
    float4 v = *(const float4*)(z + (size_t)(b0 + m) * 128 + c4);
    const float vv[4] = {v.x, v.y, v.z, v.w};
    #pragma unroll
    for (int e = 0; e < 4; ++e) {
      int off = FOFF(m, c4 + e);
      bf16 hi = (bf16)vv[e];
      zF[0][off] = hi;
      zF[1][off] = (bf16)(vv[e] - (float)hi);
    }
  }
  for (int i = tid; i < 1024; i += 512) {
    int m = i >> 6, e = i & 63;
    xf[(size_t)rt * 1024 + FOFF(m, e)] = emb[64 + e];
  }
  __syncthreads();
  f32x4 acc[6];
  #pragma unroll
  for (int t = 0; t < 6; ++t) acc[t] = splat4(z2h_b[(wv * 6 + t) * 16 + r15]);
  #pragma unroll
  for (int kt = 0; kt < 4; ++kt) {
    bf16x8 a0 = *(const bf16x8*)(&zF[0][kt * 512 + lane * 8]);
    bf16x8 a1 = *(const bf16x8*)(&zF[1][kt * 512 + lane * 8]);
    #pragma unroll
    for (int t = 0; t < 6; ++t) {
      const bf16* bb = wsb + O_Z2H + (size_t)((wv * 6 + t) * 4 + kt) * 1024 + lane * 8;
      bf16x8 b0 = *(const bf16x8*)bb;
      bf16x8 b1 = *(const bf16x8*)(bb + 512);
      acc[t] = MFMA16(a0, b0, acc[t]);
      acc[t] = MFMA16(a1, b0, acc[t]);
      acc[t] = MFMA16(a0, b1, acc[t]);
    }
  }
  #pragma unroll
  for (int t = 0; t < 6; ++t) {
    const int col = (wv * 6 + t) * 16 + r15;
    const int lay = col >> 8, j = col & 255;
    float* H = lay == 0 ? h0 : lay == 1 ? h1 : h2;
    #pragma unroll
    for (int r = 0; r < 4; ++r)
      H[(size_t)rt * 4096 + FOFF(q * 4 + r, j)] = tanhf(acc[t][r]);
  }
}

// Gate kernel, 2D-tiled: block (rg,cg) = 128 rows x 32 neurons of layer L.
// W slice staged in LDS (reg-staged) in NPH phases; A = fp32 frags from global,
// converted hi/lo in-reg; 3-pass split MFMA; h update fp32 hin->hout (dbuf).
template<int L>
__global__ __launch_bounds__(512)
void kgate(const float* __restrict__ ain, const float* __restrict__ hin,
           float* __restrict__ hout,
           const float* __restrict__ bih, const float* __restrict__ bhh,
           const bf16* __restrict__ wsb)
{
  constexpr int KTI = (L == 0) ? 2 : 8;
  constexpr int KT  = KTI + 8;
  constexpr int PH  = (L == 0) ? 10 : 8;
  constexpr int NPH = (L == 0) ? 1 : 2;
  constexpr int AST = (L == 0) ? 1024 : 4096;
  const size_t WB = (L == 0) ? O_L0 : (L == 1) ? O_L1 : O_L2;

  __shared__ __align__(16) bf16 WS[PH][6][1024];

  const int tid = threadIdx.x, wv = tid >> 6, lane = tid & 63;
  const int q = lane >> 4, r15 = lane & 15;
  const int rg = blockIdx.x >> 3, cg = blockIdx.x & 7;
  const int rt = rg * 8 + wv;                 // this wave's global rowtile

  const float* Ain = ain + (size_t)rt * AST;
  const float* Ah  = hin + (size_t)rt * 4096;

  f32x4 accR[2], accZ[2], accNI[2], accNH[2];
  #pragma unroll
  for (int c = 0; c < 2; ++c) {
    accR[c] = splat4(0.f); accZ[c] = splat4(0.f);
    accNI[c] = splat4(0.f); accNH[c] = splat4(0.f);
  }

  #pragma unroll
  for (int p = 0; p < NPH; ++p) {
    const int kb = p * PH;
    // ---- stage W phase: 6 ct x PH kt frag blocks, reg-staged ----
    for (int u = wv; u < 6 * PH; u += 8) {
      int ct = u % 6, ktp = u / 6;
      int c = (ct >> 1) * 16 + cg * 2 + (ct & 1);
      const bf16* src = wsb + WB + (size_t)(c * KT + kb + ktp) * 1024 + lane * 8;
      bf16x8 t0 = *(const bf16x8*)src;
      bf16x8 t1 = *(const bf16x8*)(src + 512);
      *(bf16x8*)(&WS[ktp][ct][lane * 8]) = t0;
      *(bf16x8*)(&WS[ktp][ct][512 + lane * 8]) = t1;
    }
    __syncthreads();
    // ---- compute phase: A prefetch depth-1, 6 ct x 3-pass MFMA per kt ----
    const float* ap0 = (kb < KTI) ? (Ain + (size_t)kb * 512 + lane * 8)
                                  : (Ah + (size_t)(kb - KTI) * 512 + lane * 8);
    float4 va = *(const float4*)ap0;
    float4 vb = *(const float4*)(ap0 + 4);
    #pragma unroll
    for (int ktp = 0; ktp < PH; ++ktp) {
      const int kt = kb + ktp;
      float4 na, nb;
      if (ktp + 1 < PH) {
        const int kn = kt + 1;
        const float* apn = (kn < KTI) ? (Ain + (size_t)kn * 512 + lane * 8)
                                      : (Ah + (size_t)(kn - KTI) * 512 + lane * 8);
        na = *(const float4*)apn;
        nb = *(const float4*)(apn + 4);
      }
      const float vv[8] = {va.x, va.y, va.z, va.w, vb.x, vb.y, vb.z, vb.w};
      bf16x8 a0, a1;
      #pragma unroll
      for (int e = 0; e < 8; ++e) {
        bf16 hi = (bf16)vv[e];
        a0[e] = hi;
        a1[e] = (bf16)(vv[e] - (float)hi);
      }
      #pragma unroll
      for (int ct = 0; ct < 6; ++ct) {
        bf16x8 b0 = *(const bf16x8*)(&WS[ktp][ct][lane * 8]);
        bf16x8 b1 = *(const bf16x8*)(&WS[ktp][ct][512 + lane * 8]);
        f32x4* acc;
        const int ctl = ct & 1;
        if (ct < 2)      acc = &accR[ctl];
        else if (ct < 4) acc = &accZ[ctl];
        else             acc = (kt < KTI) ? &accNI[ctl] : &accNH[ctl];
        *acc = MFMA16(a0, b0, *acc);
        *acc = MFMA16(a1, b0, *acc);
        *acc = MFMA16(a0, b1, *acc);
      }
      va = na; vb = nb;
    }
    if (p + 1 < NPH) __syncthreads();   // WS reuse
  }

  // ---- GRU update: fp32 hin -> hout (double-buffered, race-free) ----
  #pragma unroll
  for (int ctl = 0; ctl < 2; ++ctl) {
    const int j = cg * 32 + ctl * 16 + r15;
    const float brz = bih[j] + bhh[j];
    const float bz  = bih[256 + j] + bhh[256 + j];
    const float bni = bih[512 + j];
    const float bnh = bhh[512 + j];
    #pragma unroll
    for (int r = 0; r < 4; ++r) {
      const int m = q * 4 + r;
      const size_t idx = (size_t)rt * 4096 + FOFF(m, j);
      float rg_ = sigf(accR[ctl][r] + brz);
      float zg  = sigf(accZ[ctl][r] + bz);
      float ng  = tanhf(accNI[ctl][r] + bni + rg_ * (accNH[ctl][r] + bnh));
      float hp  = hin[idx];
      hout[idx] = (1.f - zg) * ng + zg * hp;
    }
  }
}

// logits + argmax + next-step x-frags; block = 1 rowtile (16 rows)
__global__ __launch_bounds__(512)
void klogits(const float* __restrict__ h2, float* __restrict__ xf,
             const float* __restrict__ emb, const float* __restrict__ out_b,
             const bf16* __restrict__ wsb, float* __restrict__ out, int step)
{
  __shared__ float logS2[2][16][68];
  const int tid = threadIdx.x, wv = tid >> 6, lane = tid & 63;
  const int q = lane >> 4, r15 = lane & 15;
  const int rt = blockIdx.x;
  const float* A = h2 + (size_t)rt * 4096;

  {
    const int ks = wv >> 2, tt = wv & 3;
    f32x4 acc = ks ? splat4(0.f) : splat4(out_b[tt * 16 + r15]);
    #pragma unroll
    for (int kt2 = 0; kt2 < 4; ++kt2) {
      const int kg = ks * 4 + kt2;
      float4 v0 = *(const float4*)(A + kg * 512 + lane * 8);
      float4 v1 = *(const float4*)(A + kg * 512 + lane * 8 + 4);
      const float vv[8] = {v0.x, v0.y, v0.z, v0.w, v1.x, v1.y, v1.z, v1.w};
      bf16x8 a0, a1;
      #pragma unroll
      for (int e = 0; e < 8; ++e) {
        bf16 hi = (bf16)vv[e];
        a0[e] = hi;
        a1[e] = (bf16)(vv[e] - (float)hi);
      }
      const bf16* bb = wsb + O_OUTW + (size_t)(tt * 8 + kg) * 1024 + lane * 8;
      bf16x8 b0 = *(const bf16x8*)bb;
      bf16x8 b1 = *(const bf16x8*)(bb + 512);
      acc = MFMA16(a0, b0, acc);
      acc = MFMA16(a1, b0, acc);
      acc = MFMA16(a0, b1, acc);
    }
    #pragma unroll
    for (int r = 0; r < 4; ++r)
      logS2[ks][q * 4 + r][tt * 16 + r15] = acc[r];
  }
  __syncthreads();
  #pragma unroll
  for (int k2 = 0; k2 < 2; ++k2) {
    const int rr = wv * 2 + k2;
    float v = logS2[0][rr][lane] + logS2[1][rr][lane];
    out[((size_t)(rt * 16 + rr) * NSTEP + step) * 64 + lane] = v;
    float bv = v; int bi = lane;
    #pragma unroll
    for (int d = 1; d < 64; d <<= 1) {
      float ov = __shfl_xor(bv, d);
      int   oi = __shfl_xor(bi, d);
      if (ov > bv || (ov == bv && oi < bi)) { bv = ov; bi = oi; }
    }
    xf[(size_t)rt * 1024 + FOFF(rr, lane)] = emb[(size_t)bi * 64 + lane];
  }
}

extern "C" void kernel_launch(void* const* d_in, const int* in_sizes, int n_in,
                              void* d_out, int out_size, void* d_ws, size_t ws_size,
                              hipStream_t stream) {
  bf16*  wsb = (bf16*)d_ws;
  float* wsf = (float*)d_ws;
  const float* z     = (const float*)d_in[0];
  const float* emb   = (const float*)d_in[1];
  const float* z2h_b = (const float*)d_in[3];
  const float* out_b = (const float*)d_in[5];
  const float* bih0 = (const float*)d_in[8],  *bhh0 = (const float*)d_in[9];
  const float* bih1 = (const float*)d_in[12], *bhh1 = (const float*)d_in[13];
  const float* bih2 = (const float*)d_in[16], *bhh2 = (const float*)d_in[17];
  float* out = (float*)d_out;

  float* xf    = wsf + FXF;
  float* h0[2] = {wsf + FH0A, wsf + FH0B};
  float* h1[2] = {wsf + FH1A, wsf + FH1B};
  float* h2[2] = {wsf + FH2A, wsf + FH2B};

  pack2<<<24, 256, 0, stream>>>((const float*)d_in[6],  wsb + O_L0,  48, 2, 10, 0, 64);
  pack2<<<96, 256, 0, stream>>>((const float*)d_in[7],  wsb + O_L0,  48, 8, 10, 2, 256);
  pack2<<<96, 256, 0, stream>>>((const float*)d_in[10], wsb + O_L1,  48, 8, 16, 0, 256);
  pack2<<<96, 256, 0, stream>>>((const float*)d_in[11], wsb + O_L1,  48, 8, 16, 8, 256);
  pack2<<<96, 256, 0, stream>>>((const float*)d_in[14], wsb + O_L2,  48, 8, 16, 0, 256);
  pack2<<<96, 256, 0, stream>>>((const float*)d_in[15], wsb + O_L2,  48, 8, 16, 8, 256);
  pack2<<<48, 256, 0, stream>>>((const float*)d_in[2],  wsb + O_Z2H, 48, 4, 4,  0, 128);
  pack2<<<8,  256, 0, stream>>>((const float*)d_in[4],  wsb + O_OUTW, 4, 8, 8,  0, 256);

  kinit<<<256, 512, 0, stream>>>(z, emb, z2h_b, wsb, xf, h0[0], h1[0], h2[0]);

  for (int t = 0; t < NSTEP; ++t) {
    const int p = t & 1, pn = p ^ 1;
    kgate<0><<<256, 512, 0, stream>>>(xf,     h0[p], h0[pn], bih0, bhh0, wsb);
    kgate<1><<<256, 512, 0, stream>>>(h0[pn], h1[p], h1[pn], bih1, bhh1, wsb);
    kgate<2><<<256, 512, 0, stream>>>(h1[pn], h2[p], h2[pn], bih2, bhh2, wsb);
    klogits<<<256, 512, 0, stream>>>(h2[pn], xf, emb, out_b, wsb, out, t);
  }
}